// Round 1
// baseline (168.430 us; speedup 1.0000x reference)
//
#include <hip/hip_runtime.h>
#include <stdint.h>

// Problem: B=8, S=4096, D=64 dense attention + 3 fused 64x64 linear projections.
// Plan: proj_kernel -> Qb/Kb (bf16, row-major, Q pre-scaled 1/8), Vt (bf16, transposed [b][d][s])
//       attn_kernel -> flash attention, 16x16x32 bf16 MFMA, fp32 online softmax.

#define B_ 8
#define S_ 4096
#define D_ 64

typedef short bf16x8 __attribute__((ext_vector_type(8)));
typedef float f32x4 __attribute__((ext_vector_type(4)));

#define MFMA16(a, b, c) __builtin_amdgcn_mfma_f32_16x16x32_bf16((a), (b), (c), 0, 0, 0)

static __device__ __forceinline__ unsigned short f2bf(float x) {
  union { float f; unsigned u; } v; v.f = x;
  unsigned r = v.u + 0x7FFFu + ((v.u >> 16) & 1u);   // RNE
  return (unsigned short)(r >> 16);
}
static __device__ __forceinline__ unsigned pack2bf(float a, float b) {
  return (unsigned)f2bf(a) | ((unsigned)f2bf(b) << 16);
}
static __device__ __forceinline__ void gload16(const void* g, void* l) {
  __builtin_amdgcn_global_load_lds(
      (const __attribute__((address_space(1))) unsigned int*)g,
      (__attribute__((address_space(3))) unsigned int*)l, 16, 0, 0);
}

union U8 { unsigned short s[8]; uint4 v; };

// ---------------------------------------------------------------------------
// Projection kernel: Q = (x@Wq^T + bq)/8, K = x@Wk^T + bk, V^T = (x@Wv^T + bv)^T
// grid 512 (8 batches x 64 row-tiles), block 256 (4 waves x 16 rows each)
// ---------------------------------------------------------------------------
__global__ __launch_bounds__(256) void proj_kernel(
    const float* __restrict__ x,
    const float* __restrict__ Wq, const float* __restrict__ bq,
    const float* __restrict__ Wk, const float* __restrict__ bk,
    const float* __restrict__ Wv, const float* __restrict__ bv,
    unsigned short* __restrict__ Qb, unsigned short* __restrict__ Kb,
    unsigned short* __restrict__ Vt) {
  __shared__ unsigned short xb[64 * 64];      // bf16, XOR-swizzled rows
  __shared__ unsigned short wb[3][64 * 64];   // bf16, XOR-swizzled rows (W row-major [e][d])
  __shared__ unsigned short vtmp[64 * 64];    // bf16 linear [s][e] for transpose

  const int tid = threadIdx.x;
  const int blk = blockIdx.x;
  const int batch = blk >> 6;
  const int s0 = (blk & 63) << 6;

  // ---- stage x tile (fp32 -> bf16, swizzled) ----
  {
    const int row = tid >> 2, c0 = (tid & 3) << 4;
    const float* src = x + ((size_t)(batch * S_ + s0 + row)) * D_ + c0;
    U8 a, b;
#pragma unroll
    for (int i = 0; i < 8; i++) a.s[i] = f2bf(src[i]);
#pragma unroll
    for (int i = 0; i < 8; i++) b.s[i] = f2bf(src[8 + i]);
    char* lp = (char*)xb + row * 128;
    const int swz = (row & 7) << 4;
    *(uint4*)(lp + ((c0 * 2) ^ swz)) = a.v;
    *(uint4*)(lp + ((c0 * 2 + 16) ^ swz)) = b.v;
  }
  // ---- stage W matrices (fp32 -> bf16, swizzled) ----
  {
    const int row = tid >> 2, c0 = (tid & 3) << 4;
    const int swz = (row & 7) << 4;
    const float* Ws[3] = {Wq, Wk, Wv};
#pragma unroll
    for (int m = 0; m < 3; m++) {
      const float* src = Ws[m] + row * 64 + c0;
      U8 a, b;
#pragma unroll
      for (int i = 0; i < 8; i++) a.s[i] = f2bf(src[i]);
#pragma unroll
      for (int i = 0; i < 8; i++) b.s[i] = f2bf(src[8 + i]);
      char* lp = (char*)wb[m] + row * 128;
      *(uint4*)(lp + ((c0 * 2) ^ swz)) = a.v;
      *(uint4*)(lp + ((c0 * 2 + 16) ^ swz)) = b.v;
    }
  }
  __syncthreads();

  const int lane = tid & 63;
  const int w = tid >> 6;
  const int g = lane >> 4;
  const int lr = lane & 15;

  // A fragments: 16 rows of X per wave; lane holds X[w*16+lr][g*8+j (+32)]
  bf16x8 xa0, xa1;
  {
    const int row = w * 16 + lr;
    const int swz = (row & 7) << 4;
    const char* lp = (const char*)xb + row * 128;
    xa0 = *(const bf16x8*)(lp + ((g * 16) ^ swz));
    xa1 = *(const bf16x8*)(lp + ((64 + g * 16) ^ swz));
  }

#pragma unroll
  for (int m = 0; m < 3; m++) {
    const float* bias = (m == 0) ? bq : ((m == 1) ? bk : bv);
    f32x4 acc[4];
#pragma unroll
    for (int n = 0; n < 4; n++) { acc[n][0] = 0.f; acc[n][1] = 0.f; acc[n][2] = 0.f; acc[n][3] = 0.f; }
#pragma unroll
    for (int n = 0; n < 4; n++) {
      const int erow = n * 16 + lr;
      const int swz = (erow & 7) << 4;
      const char* lp = (const char*)wb[m] + erow * 128;
      bf16x8 wb0 = *(const bf16x8*)(lp + ((g * 16) ^ swz));
      bf16x8 wb1 = *(const bf16x8*)(lp + ((64 + g * 16) ^ swz));
      acc[n] = MFMA16(xa0, wb0, acc[n]);
      acc[n] = MFMA16(xa1, wb1, acc[n]);
    }
    // D layout: row(s-local) = 4*g + reg, col(e) = 16*n + lr
    if (m < 2) {
      unsigned short* dst = (m == 0) ? Qb : Kb;
      const float sc = (m == 0) ? 0.125f : 1.0f;  // fold 1/sqrt(64) into Q
#pragma unroll
      for (int n = 0; n < 4; n++) {
        const float bv_ = bias[n * 16 + lr];
#pragma unroll
        for (int r = 0; r < 4; r++) {
          const int srow = s0 + w * 16 + g * 4 + r;
          dst[((size_t)batch * S_ + srow) * D_ + n * 16 + lr] = f2bf((acc[n][r] + bv_) * sc);
        }
      }
    } else {
      // V -> LDS for transpose
#pragma unroll
      for (int n = 0; n < 4; n++) {
        const float bv_ = bias[n * 16 + lr];
#pragma unroll
        for (int r = 0; r < 4; r++) {
          vtmp[(w * 16 + g * 4 + r) * 64 + n * 16 + lr] = f2bf(acc[n][r] + bv_);
        }
      }
    }
  }
  __syncthreads();
  // ---- transposed store of V: Vt[batch][e][s] ----
  {
    const int e = tid >> 2, sc0 = (tid & 3) << 4;
    union { unsigned short s[16]; uint4 v[2]; } o;
#pragma unroll
    for (int i = 0; i < 16; i++) o.s[i] = vtmp[(sc0 + i) * 64 + e];
    uint4* dst = (uint4*)(Vt + (size_t)batch * (64 * S_) + (size_t)e * S_ + s0 + sc0);
    dst[0] = o.v[0];
    dst[1] = o.v[1];
  }
}

// ---------------------------------------------------------------------------
// Flash attention: 512 blocks (batch = bid&7 for XCD/L2 locality, qblk = bid>>3)
// 4 waves x 16 q-rows; KV tiles of 64; swapped QK^T; P via swizzled LDS.
// ---------------------------------------------------------------------------
__global__ __launch_bounds__(256) void attn_kernel(
    const unsigned short* __restrict__ Qb, const unsigned short* __restrict__ Kb,
    const unsigned short* __restrict__ Vt, float* __restrict__ out) {
  __shared__ unsigned short Kl[64 * 64];   // [k][d] bf16, swizzled
  __shared__ unsigned short Vl[64 * 64];   // [d][k] bf16, swizzled
  __shared__ unsigned short Pl[4][16 * 64];// per-wave [q][k] bf16, swizzled

  const int bid = blockIdx.x;
  const int batch = bid & 7;   // XCD swizzle: all 64 q-blocks of a batch share an XCD L2
  const int qblk = bid >> 3;

  const int tid = threadIdx.x;
  const int lane = tid & 63;
  const int w = tid >> 6;
  const int g = lane >> 4;
  const int lr = lane & 15;

  const size_t bOff = (size_t)batch * S_ * D_;  // element offset (Qb/Kb and Vt have same size)

  // Q fragments (B-operand of swapped QK^T): lane holds Q[q0+lr][g*8+j (+32)]
  bf16x8 qa0, qa1;
  {
    const int qrow = qblk * 64 + w * 16 + lr;
    const unsigned short* qp = Qb + bOff + (size_t)qrow * D_ + g * 8;
    qa0 = *(const bf16x8*)(qp);
    qa1 = *(const bf16x8*)(qp + 32);
  }

  f32x4 oacc[4];
#pragma unroll
  for (int n = 0; n < 4; n++) { oacc[n][0] = 0.f; oacc[n][1] = 0.f; oacc[n][2] = 0.f; oacc[n][3] = 0.f; }
  float m_run = -__builtin_inff();
  float l_run = 0.f;

  // staging geometry: 8KB tile, 256 threads x 16B x 2 chunks
  const int r0 = tid >> 3;                 // 0..31
  const int cb = (tid & 7) << 4;           // 0..112
  const int swz0 = (r0 & 7) << 4;          // (r0+32)&7 == r0&7
  const int ksrc0 = r0 * 128 + (cb ^ swz0);
  const int ksrc1 = (r0 + 32) * 128 + (cb ^ swz0);
  const int vsrc0 = r0 * (S_ * 2) + (cb ^ swz0);
  const int vsrc1 = (r0 + 32) * (S_ * 2) + (cb ^ swz0);
  const int ldst0 = tid * 16;
  const int ldst1 = 4096 + tid * 16;

  const char* Kbase = (const char*)(Kb + bOff);
  const char* Vbase = (const char*)(Vt + bOff);
  char* pb = (char*)Pl[w];
  const int swzq = (lr & 7) << 4;

  for (int kt = 0; kt < S_ / 64; kt++) {
    // ---- stage K,V tiles (pre-swizzled global source, linear LDS dest) ----
    const char* kg = Kbase + (size_t)kt * (64 * D_ * 2);
    const char* vg = Vbase + (size_t)kt * 128;
    gload16(kg + ksrc0, (char*)Kl + ldst0);
    gload16(kg + ksrc1, (char*)Kl + ldst1);
    gload16(vg + vsrc0, (char*)Vl + ldst0);
    gload16(vg + vsrc1, (char*)Vl + ldst1);
    __syncthreads();   // compiler drains vmcnt before barrier

    // ---- QK^T (swapped: A=K rows, B=Q) -> S^T; lane holds 16 scores of q=lr ----
    f32x4 sacc[4];
#pragma unroll
    for (int m = 0; m < 4; m++) {
      const int krow = m * 16 + lr;
      const int swz = (krow & 7) << 4;
      const char* lp = (const char*)Kl + krow * 128;
      bf16x8 ka0 = *(const bf16x8*)(lp + ((g * 16) ^ swz));
      bf16x8 ka1 = *(const bf16x8*)(lp + ((64 + g * 16) ^ swz));
      f32x4 c; c[0] = 0.f; c[1] = 0.f; c[2] = 0.f; c[3] = 0.f;
      c = MFMA16(ka0, qa0, c);
      c = MFMA16(ka1, qa1, c);
      sacc[m] = c;
    }

    // ---- online softmax (fp32); row q = lr shared by lanes {lr, lr+16, lr+32, lr+48} ----
    float sc[16];
#pragma unroll
    for (int m = 0; m < 4; m++)
#pragma unroll
      for (int r = 0; r < 4; r++) sc[m * 4 + r] = sacc[m][r];

    float tmax = sc[0];
#pragma unroll
    for (int i = 1; i < 16; i++) tmax = fmaxf(tmax, sc[i]);
    tmax = fmaxf(tmax, __shfl_xor(tmax, 16));
    tmax = fmaxf(tmax, __shfl_xor(tmax, 32));
    const float mnew = fmaxf(m_run, tmax);
    const float fac = __expf(m_run - mnew);
    m_run = mnew;

    float ls = 0.f;
#pragma unroll
    for (int i = 0; i < 16; i++) {
      const float p = __expf(sc[i] - mnew);
      sc[i] = p;
      ls += p;
    }
    ls += __shfl_xor(ls, 16);
    ls += __shfl_xor(ls, 32);
    l_run = l_run * fac + ls;

    // rescale O accumulators (rows q = 4g+reg need factor from lane 4g+reg)
#pragma unroll
    for (int r = 0; r < 4; r++) {
      const float fr = __shfl(fac, 4 * g + r);
#pragma unroll
      for (int n = 0; n < 4; n++) oacc[n][r] *= fr;
    }

    // ---- P -> LDS (bf16, swizzled); lane q=lr owns keys k = 16m+4g+{0..3} ----
#pragma unroll
    for (int m = 0; m < 4; m++) {
      const int k0 = m * 16 + g * 4;
      *(unsigned*)(pb + lr * 128 + ((k0 * 2) ^ swzq)) = pack2bf(sc[m * 4 + 0], sc[m * 4 + 1]);
      *(unsigned*)(pb + lr * 128 + ((k0 * 2 + 4) ^ swzq)) = pack2bf(sc[m * 4 + 2], sc[m * 4 + 3]);
    }
    // wave-local: DS ops in-order, compiler inserts lgkmcnt waits for the reads below

    // ---- PV: A = P[16q x 64k], B = V[64k x 64d] (from transposed Vl) ----
    bf16x8 pa0 = *(const bf16x8*)(pb + lr * 128 + ((g * 16) ^ swzq));
    bf16x8 pa1 = *(const bf16x8*)(pb + lr * 128 + ((64 + g * 16) ^ swzq));
#pragma unroll
    for (int n = 0; n < 4; n++) {
      const int drow = n * 16 + lr;
      const int swz = (drow & 7) << 4;
      const char* vp = (const char*)Vl + drow * 128;
      bf16x8 vb0 = *(const bf16x8*)(vp + ((g * 16) ^ swz));
      bf16x8 vb1 = *(const bf16x8*)(vp + ((64 + g * 16) ^ swz));
      oacc[n] = MFMA16(pa0, vb0, oacc[n]);
      oacc[n] = MFMA16(pa1, vb1, oacc[n]);
    }
    __syncthreads();   // protect Kl/Vl before next stage
  }

  // ---- epilogue: divide by softmax denom, store fp32 ----
  float linv[4];
#pragma unroll
  for (int r = 0; r < 4; r++) linv[r] = 1.0f / __shfl(l_run, 4 * g + r);

  const int qrow0 = qblk * 64 + w * 16;
#pragma unroll
  for (int n = 0; n < 4; n++) {
#pragma unroll
    for (int r = 0; r < 4; r++) {
      out[((size_t)batch * S_ + qrow0 + 4 * g + r) * D_ + n * 16 + lr] = oacc[n][r] * linv[r];
    }
  }
}

// ---------------------------------------------------------------------------
extern "C" void kernel_launch(void* const* d_in, const int* in_sizes, int n_in,
                              void* d_out, int out_size, void* d_ws, size_t ws_size,
                              hipStream_t stream) {
  const float* x  = (const float*)d_in[0];
  const float* Wq = (const float*)d_in[1];
  const float* bq = (const float*)d_in[2];
  const float* Wk = (const float*)d_in[3];
  const float* bk = (const float*)d_in[4];
  const float* Wv = (const float*)d_in[5];
  const float* bv = (const float*)d_in[6];

  unsigned short* Qb = (unsigned short*)d_ws;            // bf16 [8][4096][64], Q pre-scaled 1/8
  unsigned short* Kb = Qb + (size_t)B_ * S_ * D_;        // bf16 [8][4096][64]
  unsigned short* Vt = Kb + (size_t)B_ * S_ * D_;        // bf16 [8][64][4096]

  proj_kernel<<<512, 256, 0, stream>>>(x, Wq, bq, Wk, bk, Wv, bv, Qb, Kb, Vt);
  attn_kernel<<<512, 256, 0, stream>>>(Qb, Kb, Vt, (float*)d_out);
}

// Round 2
// 131.742 us; speedup vs baseline: 1.2785x; 1.2785x over previous
//
#include <hip/hip_runtime.h>
#include <stdint.h>

// B=8, S=4096, D=64 dense attention + 3 fused 64x64 linear projections.
// proj_kernel: Qb (bf16, pre-scaled log2e/8), Kb (bf16 row-major),
//              Vt (bf16, [b][d][s] with per-32 k-permutation pi0)
// attn_kernel: flash attn, 16x16x32 bf16 MFMA, base-2 online softmax,
//              q=32/wave, intra-block KV-split (2 q-halves x 2 kv-halves),
//              in-register P via k-permutation, double-buffered gload_lds.

#define B_ 8
#define S_ 4096
#define D_ 64
#define THR 7.0f

typedef short bf16x8 __attribute__((ext_vector_type(8)));
typedef float f32x4 __attribute__((ext_vector_type(4)));

#define MFMA16(a, b, c) __builtin_amdgcn_mfma_f32_16x16x32_bf16((a), (b), (c), 0, 0, 0)

static __device__ __forceinline__ unsigned short f2bf(float x) {
  union { float f; unsigned u; } v; v.f = x;
  unsigned r = v.u + 0x7FFFu + ((v.u >> 16) & 1u);   // RNE
  return (unsigned short)(r >> 16);
}
static __device__ __forceinline__ void gload16(const void* g, void* l) {
  __builtin_amdgcn_global_load_lds(
      (const __attribute__((address_space(1))) unsigned int*)g,
      (__attribute__((address_space(3))) unsigned int*)l, 16, 0, 0);
}

union U8 { unsigned short s[8]; uint4 v; };
union PB { int w[4]; bf16x8 v; };

// ---------------------------------------------------------------------------
// Projection kernel. grid 512 (8 batches x 64 row-tiles), block 256.
// ---------------------------------------------------------------------------
__global__ __launch_bounds__(256) void proj_kernel(
    const float* __restrict__ x,
    const float* __restrict__ Wq, const float* __restrict__ bq,
    const float* __restrict__ Wk, const float* __restrict__ bk,
    const float* __restrict__ Wv, const float* __restrict__ bv,
    unsigned short* __restrict__ Qb, unsigned short* __restrict__ Kb,
    unsigned short* __restrict__ Vt) {
  __shared__ unsigned short xb[64 * 64];      // bf16, XOR-swizzled rows
  __shared__ unsigned short wb[3][64 * 64];   // bf16, XOR-swizzled rows
  __shared__ unsigned short vtmp[64 * 64];    // bf16 linear [s][e] for transpose

  const int tid = threadIdx.x;
  const int blk = blockIdx.x;
  const int batch = blk >> 6;
  const int s0 = (blk & 63) << 6;

  {
    const int row = tid >> 2, c0 = (tid & 3) << 4;
    const float* src = x + ((size_t)(batch * S_ + s0 + row)) * D_ + c0;
    U8 a, b;
#pragma unroll
    for (int i = 0; i < 8; i++) a.s[i] = f2bf(src[i]);
#pragma unroll
    for (int i = 0; i < 8; i++) b.s[i] = f2bf(src[8 + i]);
    char* lp = (char*)xb + row * 128;
    const int swz = (row & 7) << 4;
    *(uint4*)(lp + ((c0 * 2) ^ swz)) = a.v;
    *(uint4*)(lp + ((c0 * 2 + 16) ^ swz)) = b.v;
  }
  {
    const int row = tid >> 2, c0 = (tid & 3) << 4;
    const int swz = (row & 7) << 4;
    const float* Ws[3] = {Wq, Wk, Wv};
#pragma unroll
    for (int m = 0; m < 3; m++) {
      const float* src = Ws[m] + row * 64 + c0;
      U8 a, b;
#pragma unroll
      for (int i = 0; i < 8; i++) a.s[i] = f2bf(src[i]);
#pragma unroll
      for (int i = 0; i < 8; i++) b.s[i] = f2bf(src[8 + i]);
      char* lp = (char*)wb[m] + row * 128;
      *(uint4*)(lp + ((c0 * 2) ^ swz)) = a.v;
      *(uint4*)(lp + ((c0 * 2 + 16) ^ swz)) = b.v;
    }
  }
  __syncthreads();

  const int lane = tid & 63;
  const int w = tid >> 6;
  const int g = lane >> 4;
  const int lr = lane & 15;

  bf16x8 xa0, xa1;
  {
    const int row = w * 16 + lr;
    const int swz = (row & 7) << 4;
    const char* lp = (const char*)xb + row * 128;
    xa0 = *(const bf16x8*)(lp + ((g * 16) ^ swz));
    xa1 = *(const bf16x8*)(lp + ((64 + g * 16) ^ swz));
  }

#pragma unroll
  for (int m = 0; m < 3; m++) {
    const float* bias = (m == 0) ? bq : ((m == 1) ? bk : bv);
    f32x4 acc[4];
#pragma unroll
    for (int n = 0; n < 4; n++) { acc[n][0] = 0.f; acc[n][1] = 0.f; acc[n][2] = 0.f; acc[n][3] = 0.f; }
#pragma unroll
    for (int n = 0; n < 4; n++) {
      const int erow = n * 16 + lr;
      const int swz = (erow & 7) << 4;
      const char* lp = (const char*)wb[m] + erow * 128;
      bf16x8 wb0 = *(const bf16x8*)(lp + ((g * 16) ^ swz));
      bf16x8 wb1 = *(const bf16x8*)(lp + ((64 + g * 16) ^ swz));
      acc[n] = MFMA16(xa0, wb0, acc[n]);
      acc[n] = MFMA16(xa1, wb1, acc[n]);
    }
    if (m < 2) {
      unsigned short* dst = (m == 0) ? Qb : Kb;
      // Q folds 1/sqrt(64) AND log2(e) (softmax runs in base-2 domain)
      const float sc = (m == 0) ? 0.18033688011112042f : 1.0f;
#pragma unroll
      for (int n = 0; n < 4; n++) {
        const float bv_ = bias[n * 16 + lr];
#pragma unroll
        for (int r = 0; r < 4; r++) {
          const int srow = s0 + w * 16 + g * 4 + r;
          dst[((size_t)batch * S_ + srow) * D_ + n * 16 + lr] = f2bf((acc[n][r] + bv_) * sc);
        }
      }
    } else {
#pragma unroll
      for (int n = 0; n < 4; n++) {
        const float bv_ = bias[n * 16 + lr];
#pragma unroll
        for (int r = 0; r < 4; r++) {
          vtmp[(w * 16 + g * 4 + r) * 64 + n * 16 + lr] = f2bf(acc[n][r] + bv_);
        }
      }
    }
  }
  __syncthreads();
  // Transposed + k-permuted store of V: Vt[b][e][s'] = V[(s'&~31)+pi0(s'&31)][e]
  // pi0(u) = 16*((u>>2)&1) + 4*(u>>3) + (u&3)  (bijection on [0,32))
  {
    const int e = tid >> 2, sc0 = (tid & 3) << 4;
    union { unsigned short s[16]; uint4 v[2]; } o;
#pragma unroll
    for (int i = 0; i < 16; i++) {
      const int sp = sc0 + i;
      const int u = sp & 31;
      const int kap = (sp & 32) + 16 * ((u >> 2) & 1) + 4 * (u >> 3) + (u & 3);
      o.s[i] = vtmp[kap * 64 + e];
    }
    uint4* dst = (uint4*)(Vt + (size_t)batch * (64 * S_) + (size_t)e * S_ + s0 + sc0);
    dst[0] = o.v[0];
    dst[1] = o.v[1];
  }
}

// ---------------------------------------------------------------------------
// Flash attention. grid 512 (batch = bid&7 for XCD/L2 locality), block 256.
// wave w: q-half = w&1 (32 q rows), kv-half = w>>1 (32 of 64 KV tiles).
// ---------------------------------------------------------------------------
__global__ __launch_bounds__(256, 2) void attn_kernel(
    const unsigned short* __restrict__ Qb, const unsigned short* __restrict__ Kb,
    const unsigned short* __restrict__ Vt, float* __restrict__ out) {
  // LDS: buf[2] x half[2] x (K 8KB | V 8KB) = 64KB; merge reuses buf0.
  __shared__ char lds[65536];

  const int bid = blockIdx.x;
  const int batch = bid & 7;
  const int qblk = bid >> 3;
  const int tid = threadIdx.x;
  const int lane = tid & 63;
  const int w = tid >> 6;
  const int qh = w & 1;
  const int kh = w >> 1;
  const int lr = lane & 15;
  const int g = lane >> 4;
  const int swzR = (lr & 7) << 4;

  const size_t bOff = (size_t)batch * S_ * D_;

  // Q B-fragments: lane holds Q[qbase + qs*16 + lr][g*8+j (+32)]
  bf16x8 qa[2][2];
  {
    const unsigned short* qbase = Qb + bOff + ((size_t)(qblk * 64 + qh * 32 + lr)) * D_;
    qa[0][0] = *(const bf16x8*)(qbase + g * 8);
    qa[0][1] = *(const bf16x8*)(qbase + 32 + g * 8);
    qa[1][0] = *(const bf16x8*)(qbase + 16 * D_ + g * 8);
    qa[1][1] = *(const bf16x8*)(qbase + 16 * D_ + 32 + g * 8);
  }

  f32x4 oacc[2][4];
#pragma unroll
  for (int qs = 0; qs < 2; qs++)
#pragma unroll
    for (int n = 0; n < 4; n++) { oacc[qs][n][0] = 0.f; oacc[qs][n][1] = 0.f; oacc[qs][n][2] = 0.f; oacc[qs][n][3] = 0.f; }
  float m_[2] = {-__builtin_inff(), -__builtin_inff()};
  float l_[2] = {0.f, 0.f};

  // ---- staging geometry (wave 0: K half0, wave 1: V half0, wave 2/3: half1) ----
  const int rsub = lane >> 3;                        // 0..7
  const int csw = (((lane & 7) ^ rsub)) << 4;        // pre-swizzled col within 128B row
  const char* KbaseB = (const char*)(Kb + bOff);
  const char* VbaseB = (const char*)(Vt + bOff);
  const int sh = w >> 1;                             // which kv-half this wave stages
  const bool stK = ((w & 1) == 0);
  const char* ksrcBase = KbaseB + rsub * 128 + csw;  // + kt*8192 + c*1024
  const char* vsrcBase = VbaseB + rsub * 8192 + csw; // + kt*128  + c*65536
  char* const stagedst = lds + (sh << 14) + ((w & 1) << 13);

  auto STAGE = [&](int t, int buf) {
    const int kt = sh * 32 + t;
    char* ldst = stagedst + buf * 32768;
    if (stK) {
      const char* s0 = ksrcBase + (size_t)kt * 8192;
#pragma unroll
      for (int c = 0; c < 8; c++) gload16(s0 + c * 1024, ldst + c * 1024);
    } else {
      const char* s0 = vsrcBase + (size_t)kt * 128;
#pragma unroll
      for (int c = 0; c < 8; c++) gload16(s0 + c * 65536, ldst + c * 1024);
    }
  };

  STAGE(0, 0);
  __syncthreads();

  for (int t = 0; t < 32; t++) {
    const int buf = t & 1;
    if (t < 31) STAGE(t + 1, buf ^ 1);

    const char* Kl = lds + buf * 32768 + (kh << 14);
    const char* Vl = Kl + 8192;

    // ---- QK^T (swapped: A=K rows, B=Q): lane holds S[q=lr][k=16m+4g+r] ----
    f32x4 sacc[2][4];
#pragma unroll
    for (int m = 0; m < 4; m++) {
      const char* kp = Kl + (m * 16 + lr) * 128;
      bf16x8 ka0 = *(const bf16x8*)(kp + ((g * 16) ^ swzR));
      bf16x8 ka1 = *(const bf16x8*)(kp + ((64 + g * 16) ^ swzR));
#pragma unroll
      for (int qs = 0; qs < 2; qs++) {
        f32x4 c; c[0] = 0.f; c[1] = 0.f; c[2] = 0.f; c[3] = 0.f;
        c = MFMA16(ka0, qa[qs][0], c);
        c = MFMA16(ka1, qa[qs][1], c);
        sacc[qs][m] = c;
      }
    }

    // ---- online softmax, base-2 domain ----
    float rmax[2];
#pragma unroll
    for (int qs = 0; qs < 2; qs++) {
      float mx = sacc[qs][0][0];
#pragma unroll
      for (int m = 0; m < 4; m++)
#pragma unroll
        for (int r = 0; r < 4; r++) mx = fmaxf(mx, sacc[qs][m][r]);
      mx = fmaxf(mx, __shfl_xor(mx, 16));
      mx = fmaxf(mx, __shfl_xor(mx, 32));
      rmax[qs] = mx;
    }
    const bool ok = (rmax[0] <= m_[0] + THR) && (rmax[1] <= m_[1] + THR);
    if (!__all(ok)) {   // defer-rescale: only pay the O-rescale on real max growth
#pragma unroll
      for (int qs = 0; qs < 2; qs++) {
        const float mn = fmaxf(m_[qs], rmax[qs]);
        const float fac = __builtin_amdgcn_exp2f(m_[qs] - mn);
        m_[qs] = mn;
        l_[qs] *= fac;
#pragma unroll
        for (int n = 0; n < 4; n++) oacc[qs][n] *= fac;
      }
    }

    float p[2][16];
#pragma unroll
    for (int qs = 0; qs < 2; qs++) {
      float s = 0.f;
#pragma unroll
      for (int m = 0; m < 4; m++)
#pragma unroll
        for (int r = 0; r < 4; r++) {
          const float pv = __builtin_amdgcn_exp2f(sacc[qs][m][r] - m_[qs]);
          p[qs][m * 4 + r] = pv;
          s += pv;
        }
      s += __shfl_xor(s, 16);
      s += __shfl_xor(s, 32);
      l_[qs] += s;
    }

    // ---- P -> bf16 fragments, fully lane-local (k-permuted V layout) ----
    PB pb[2][2];
#pragma unroll
    for (int qs = 0; qs < 2; qs++)
#pragma unroll
      for (int i = 0; i < 8; i++) {
        int r_;
        asm("v_cvt_pk_bf16_f32 %0, %1, %2" : "=v"(r_) : "v"(p[qs][2 * i]), "v"(p[qs][2 * i + 1]));
        pb[qs][i >> 2].w[i & 3] = r_;
      }

    // ---- PV (swapped: A=V^T rows, B=P^T): D[d-local][q=lr] ----
#pragma unroll
    for (int n = 0; n < 4; n++) {
      const char* vp = Vl + (n * 16 + lr) * 128;
      bf16x8 va0 = *(const bf16x8*)(vp + ((g * 16) ^ swzR));
      bf16x8 va1 = *(const bf16x8*)(vp + ((64 + g * 16) ^ swzR));
#pragma unroll
      for (int qs = 0; qs < 2; qs++) {
        oacc[qs][n] = MFMA16(va0, pb[qs][0].v, oacc[qs][n]);
        oacc[qs][n] = MFMA16(va1, pb[qs][1].v, oacc[qs][n]);
      }
    }
    __syncthreads();
  }

  // ---- merge kv-halves (partner wave = w^2, same q rows, same lane layout) ----
  char* mbase = lds + (qh << 14);
  if (kh == 1) {
#pragma unroll
    for (int qs = 0; qs < 2; qs++) {
      const int q = qs * 16 + lr;
      char* row = mbase + q * 256;
#pragma unroll
      for (int n = 0; n < 4; n++)
        *(f32x4*)(row + ((n * 64 + g * 16) ^ ((lr & 7) << 4))) = oacc[qs][n];
    }
    if (g == 0) {
#pragma unroll
      for (int qs = 0; qs < 2; qs++) {
        float2 ml; ml.x = m_[qs]; ml.y = l_[qs];
        *(float2*)(mbase + 8192 + qs * 128 + lr * 8) = ml;
      }
    }
  }
  __syncthreads();
  if (kh == 0) {
#pragma unroll
    for (int qs = 0; qs < 2; qs++) {
      const float2 ml2 = *(const float2*)(mbase + 8192 + qs * 128 + lr * 8);
      const float mn = fmaxf(m_[qs], ml2.x);
      const float a1 = __builtin_amdgcn_exp2f(m_[qs] - mn);
      const float a2 = __builtin_amdgcn_exp2f(ml2.x - mn);
      const float inv = 1.0f / (l_[qs] * a1 + ml2.y * a2);
      const int q = qs * 16 + lr;
      const char* row = mbase + q * 256;
      float* orow = out + ((size_t)batch * S_ + qblk * 64 + qh * 32 + q) * D_;
#pragma unroll
      for (int n = 0; n < 4; n++) {
        f32x4 o2 = *(const f32x4*)(row + ((n * 64 + g * 16) ^ ((lr & 7) << 4)));
        f32x4 res = (oacc[qs][n] * a1 + o2 * a2) * inv;
        *(f32x4*)(orow + n * 16 + g * 4) = res;
      }
    }
  }
}

// ---------------------------------------------------------------------------
extern "C" void kernel_launch(void* const* d_in, const int* in_sizes, int n_in,
                              void* d_out, int out_size, void* d_ws, size_t ws_size,
                              hipStream_t stream) {
  const float* x  = (const float*)d_in[0];
  const float* Wq = (const float*)d_in[1];
  const float* bq = (const float*)d_in[2];
  const float* Wk = (const float*)d_in[3];
  const float* bk = (const float*)d_in[4];
  const float* Wv = (const float*)d_in[5];
  const float* bv = (const float*)d_in[6];

  unsigned short* Qb = (unsigned short*)d_ws;            // bf16, pre-scaled log2e/8
  unsigned short* Kb = Qb + (size_t)B_ * S_ * D_;        // bf16 row-major
  unsigned short* Vt = Kb + (size_t)B_ * S_ * D_;        // bf16 [b][d][s], k-permuted

  proj_kernel<<<512, 256, 0, stream>>>(x, Wq, bq, Wk, bk, Wv, bv, Qb, Kb, Vt);
  attn_kernel<<<512, 256, 0, stream>>>(Qb, Kb, Vt, (float*)d_out);
}

// Round 4
// 125.073 us; speedup vs baseline: 1.3467x; 1.0533x over previous
//
#include <hip/hip_runtime.h>
#include <stdint.h>

// B=8, S=4096, D=64 dense attention + 3 fused 64x64 linear projections.
// proj_kernel: Qb (bf16, pre-scaled log2e/8), Kb (bf16 row-major),
//              Vt (bf16, [b][d][s] with per-32 k-permutation pi0).
//              Q/K bounced through swizzled LDS -> dwordx4 stores; V via
//              linear vtmp (round-2 known-good path).
// attn_kernel: round-2 single-barrier flash loop (known-good), 16x16x32 bf16
//              MFMA, base-2 online softmax with lane-local defer check,
//              tree sums, lane-partial l, setprio around MFMA groups.

#define B_ 8
#define S_ 4096
#define D_ 64
#define THR 7.0f

typedef short bf16x8 __attribute__((ext_vector_type(8)));
typedef float f32x4 __attribute__((ext_vector_type(4)));

#define MFMA16(a, b, c) __builtin_amdgcn_mfma_f32_16x16x32_bf16((a), (b), (c), 0, 0, 0)

static __device__ __forceinline__ unsigned short f2bf(float x) {
  union { float f; unsigned u; } v; v.f = x;
  unsigned r = v.u + 0x7FFFu + ((v.u >> 16) & 1u);   // RNE
  return (unsigned short)(r >> 16);
}
static __device__ __forceinline__ void gload16(const void* g, void* l) {
  __builtin_amdgcn_global_load_lds(
      (const __attribute__((address_space(1))) unsigned int*)g,
      (__attribute__((address_space(3))) unsigned int*)l, 16, 0, 0);
}

union U8 { unsigned short s[8]; uint4 v; };
union PB { int w[4]; bf16x8 v; };

// ---------------------------------------------------------------------------
// Projection kernel. grid 512 (8 batches x 64 row-tiles), block 256.
// ---------------------------------------------------------------------------
__global__ __launch_bounds__(256) void proj_kernel(
    const float* __restrict__ x,
    const float* __restrict__ Wq, const float* __restrict__ bq,
    const float* __restrict__ Wk, const float* __restrict__ bk,
    const float* __restrict__ Wv, const float* __restrict__ bv,
    unsigned short* __restrict__ Qb, unsigned short* __restrict__ Kb,
    unsigned short* __restrict__ Vt) {
  __shared__ unsigned short xb[64 * 64];      // bf16, XOR-swizzled rows; reused for Q bounce
  __shared__ unsigned short wb[3][64 * 64];   // bf16, XOR-swizzled rows; wb[0] reused for K bounce
  __shared__ unsigned short vtmp[64 * 64];    // bf16 LINEAR [s][e] for V transpose (round-2 path)

  const int tid = threadIdx.x;
  const int blk = blockIdx.x;
  const int batch = blk >> 6;
  const int s0 = (blk & 63) << 6;

  const int row = tid >> 2, c0 = (tid & 3) << 4;
  const int sw = (row & 7) << 4;

  // ---- stage x tile (fp32 -> bf16, swizzled) ----
  {
    const float* src = x + ((size_t)(batch * S_ + s0 + row)) * D_ + c0;
    U8 a, b;
#pragma unroll
    for (int i = 0; i < 8; i++) a.s[i] = f2bf(src[i]);
#pragma unroll
    for (int i = 0; i < 8; i++) b.s[i] = f2bf(src[8 + i]);
    char* lp = (char*)xb + row * 128;
    *(uint4*)(lp + ((c0 * 2) ^ sw)) = a.v;
    *(uint4*)(lp + ((c0 * 2 + 16) ^ sw)) = b.v;
  }
  // ---- stage W matrices (fp32 -> bf16, swizzled) ----
  {
    const float* Ws[3] = {Wq, Wk, Wv};
#pragma unroll
    for (int m = 0; m < 3; m++) {
      const float* src = Ws[m] + row * 64 + c0;
      U8 a, b;
#pragma unroll
      for (int i = 0; i < 8; i++) a.s[i] = f2bf(src[i]);
#pragma unroll
      for (int i = 0; i < 8; i++) b.s[i] = f2bf(src[8 + i]);
      char* lp = (char*)wb[m] + row * 128;
      *(uint4*)(lp + ((c0 * 2) ^ sw)) = a.v;
      *(uint4*)(lp + ((c0 * 2 + 16) ^ sw)) = b.v;
    }
  }
  __syncthreads();

  const int lane = tid & 63;
  const int w = tid >> 6;
  const int g = lane >> 4;
  const int lr = lane & 15;

  bf16x8 xa0, xa1;
  {
    const int xr = w * 16 + lr;
    const int swz = (xr & 7) << 4;
    const char* lp = (const char*)xb + xr * 128;
    xa0 = *(const bf16x8*)(lp + ((g * 16) ^ swz));
    xa1 = *(const bf16x8*)(lp + ((64 + g * 16) ^ swz));
  }

  f32x4 acc[3][4];
#pragma unroll
  for (int m = 0; m < 3; m++)
#pragma unroll
    for (int n = 0; n < 4; n++) { acc[m][n][0] = 0.f; acc[m][n][1] = 0.f; acc[m][n][2] = 0.f; acc[m][n][3] = 0.f; }
#pragma unroll
  for (int m = 0; m < 3; m++) {
#pragma unroll
    for (int n = 0; n < 4; n++) {
      const int erow = n * 16 + lr;
      const int swz = (erow & 7) << 4;
      const char* lp = (const char*)wb[m] + erow * 128;
      bf16x8 w0 = *(const bf16x8*)(lp + ((g * 16) ^ swz));
      bf16x8 w1 = *(const bf16x8*)(lp + ((64 + g * 16) ^ swz));
      acc[m][n] = MFMA16(xa0, w0, acc[m][n]);
      acc[m][n] = MFMA16(xa1, w1, acc[m][n]);
    }
  }
  __syncthreads();   // all fragment reads done -> xb / wb[0] / vtmp reusable

  // ---- bounce: Q -> xb (swizzled), K -> wb[0] (swizzled), V -> vtmp (linear) ----
  // D layout: row(s-local) = w*16 + 4*g + reg, col(e) = 16*n + lr
  {
#pragma unroll
    for (int n = 0; n < 4; n++) {
      const float bq_ = bq[n * 16 + lr];
      const float bk_ = bk[n * 16 + lr];
      const float bv_ = bv[n * 16 + lr];
#pragma unroll
      for (int r = 0; r < 4; r++) {
        const int orow = w * 16 + 4 * g + r;
        const int cb = ((n * 16 + lr) * 2) ^ ((orow & 7) << 4);
        *(unsigned short*)((char*)xb + orow * 128 + cb) =
            f2bf((acc[0][n][r] + bq_) * 0.18033688011112042f);   // (1/8)*log2(e) into Q
        *(unsigned short*)((char*)wb[0] + orow * 128 + cb) = f2bf(acc[1][n][r] + bk_);
        vtmp[orow * 64 + n * 16 + lr] = f2bf(acc[2][n][r] + bv_);
      }
    }
  }
  __syncthreads();

  // ---- coalesced wide stores ----
  {
    const char* qs_ = (const char*)xb + row * 128;
    uint4 q0 = *(const uint4*)(qs_ + ((c0 * 2) ^ sw));
    uint4 q1 = *(const uint4*)(qs_ + ((c0 * 2 + 16) ^ sw));
    unsigned short* qd = Qb + ((size_t)batch * S_ + s0 + row) * D_ + c0;
    *(uint4*)qd = q0;
    *(uint4*)(qd + 8) = q1;

    const char* ks_ = (const char*)wb[0] + row * 128;
    uint4 k0 = *(const uint4*)(ks_ + ((c0 * 2) ^ sw));
    uint4 k1 = *(const uint4*)(ks_ + ((c0 * 2 + 16) ^ sw));
    unsigned short* kd = Kb + ((size_t)batch * S_ + s0 + row) * D_ + c0;
    *(uint4*)kd = k0;
    *(uint4*)(kd + 8) = k1;

    // Vt[b][e][s'] = V[(s'&~31)+pi0(s'&31)][e]; pi0(u)=16*((u>>2)&1)+4*(u>>3)+(u&3)
    const int e = row, sc0 = c0;
    union { unsigned short s[16]; uint4 v[2]; } o;
#pragma unroll
    for (int i = 0; i < 16; i++) {
      const int sp = sc0 + i;
      const int u = sp & 31;
      const int kap = (sp & 32) + 16 * ((u >> 2) & 1) + 4 * (u >> 3) + (u & 3);
      o.s[i] = vtmp[kap * 64 + e];
    }
    uint4* dst = (uint4*)(Vt + (size_t)batch * (64 * S_) + (size_t)e * S_ + s0 + sc0);
    dst[0] = o.v[0];
    dst[1] = o.v[1];
  }
}

// ---------------------------------------------------------------------------
// Flash attention. grid 512 (batch = bid&7 for XCD/L2 locality), block 256.
// wave w: q-half = w&1 (32 q rows), kv-half = w>>1 (32 of 64 KV tiles).
// Round-2 single-barrier loop structure (known-good).
// ---------------------------------------------------------------------------
__global__ __launch_bounds__(256, 2) void attn_kernel(
    const unsigned short* __restrict__ Qb, const unsigned short* __restrict__ Kb,
    const unsigned short* __restrict__ Vt, float* __restrict__ out) {
  __shared__ char lds[65536];   // buf[2] x half[2] x (K 8KB | V 8KB)

  const int bid = blockIdx.x;
  const int batch = bid & 7;
  const int qblk = bid >> 3;
  const int tid = threadIdx.x;
  const int lane = tid & 63;
  const int w = tid >> 6;
  const int qh = w & 1;
  const int kh = w >> 1;
  const int lr = lane & 15;
  const int g = lane >> 4;
  const int swzR = (lr & 7) << 4;

  const size_t bOff = (size_t)batch * S_ * D_;

  bf16x8 qa[2][2];
  {
    const unsigned short* qbase = Qb + bOff + ((size_t)(qblk * 64 + qh * 32 + lr)) * D_;
    qa[0][0] = *(const bf16x8*)(qbase + g * 8);
    qa[0][1] = *(const bf16x8*)(qbase + 32 + g * 8);
    qa[1][0] = *(const bf16x8*)(qbase + 16 * D_ + g * 8);
    qa[1][1] = *(const bf16x8*)(qbase + 16 * D_ + 32 + g * 8);
  }

  f32x4 oacc[2][4];
#pragma unroll
  for (int qs = 0; qs < 2; qs++)
#pragma unroll
    for (int n = 0; n < 4; n++) { oacc[qs][n][0] = 0.f; oacc[qs][n][1] = 0.f; oacc[qs][n][2] = 0.f; oacc[qs][n][3] = 0.f; }
  float m_[2] = {-__builtin_inff(), -__builtin_inff()};
  float l_[2] = {0.f, 0.f};   // lane-partial; reduced across g pre-merge

  const int rsub = lane >> 3;
  const int csw = (((lane & 7) ^ rsub)) << 4;
  const char* KbaseB = (const char*)(Kb + bOff);
  const char* VbaseB = (const char*)(Vt + bOff);
  const int sh = w >> 1;
  const bool stK = ((w & 1) == 0);
  const char* ksrcBase = KbaseB + rsub * 128 + csw;
  const char* vsrcBase = VbaseB + rsub * 8192 + csw;
  char* const stagedst = lds + (sh << 14) + ((w & 1) << 13);

  auto STAGE = [&](int t, int buf) {
    const int kt = sh * 32 + t;
    char* ldst = stagedst + buf * 32768;
    if (stK) {
      const char* s0_ = ksrcBase + (size_t)kt * 8192;
#pragma unroll
      for (int c = 0; c < 8; c++) gload16(s0_ + c * 1024, ldst + c * 1024);
    } else {
      const char* s0_ = vsrcBase + (size_t)kt * 128;
#pragma unroll
      for (int c = 0; c < 8; c++) gload16(s0_ + c * 65536, ldst + c * 1024);
    }
  };

  f32x4 sacc[2][4];
  PB pb[2][2];

#define SOFTMAX_STEP()                                                                     \
  {                                                                                        \
    float lmax[2];                                                                         \
    _Pragma("unroll") for (int qs = 0; qs < 2; qs++) {                                     \
      float a0 = fmaxf(fmaxf(sacc[qs][0][0], sacc[qs][0][1]), fmaxf(sacc[qs][0][2], sacc[qs][0][3])); \
      float a1 = fmaxf(fmaxf(sacc[qs][1][0], sacc[qs][1][1]), fmaxf(sacc[qs][1][2], sacc[qs][1][3])); \
      float a2 = fmaxf(fmaxf(sacc[qs][2][0], sacc[qs][2][1]), fmaxf(sacc[qs][2][2], sacc[qs][2][3])); \
      float a3 = fmaxf(fmaxf(sacc[qs][3][0], sacc[qs][3][1]), fmaxf(sacc[qs][3][2], sacc[qs][3][3])); \
      lmax[qs] = fmaxf(fmaxf(a0, a1), fmaxf(a2, a3));                                      \
    }                                                                                      \
    const bool ok = (lmax[0] <= m_[0] + THR) && (lmax[1] <= m_[1] + THR);                  \
    if (!__all(ok)) {                                                                      \
      _Pragma("unroll") for (int qs = 0; qs < 2; qs++) {                                   \
        float mx = fmaxf(lmax[qs], __shfl_xor(lmax[qs], 16));                              \
        mx = fmaxf(mx, __shfl_xor(mx, 32));                                                \
        const float mn = fmaxf(m_[qs], mx);                                                \
        const float fac = __builtin_amdgcn_exp2f(m_[qs] - mn);                             \
        m_[qs] = mn;                                                                       \
        l_[qs] *= fac;                                                                     \
        _Pragma("unroll") for (int n = 0; n < 4; n++) oacc[qs][n] *= fac;                  \
      }                                                                                    \
    }                                                                                      \
    _Pragma("unroll") for (int qs = 0; qs < 2; qs++) {                                     \
      float p[16];                                                                         \
      _Pragma("unroll") for (int mm = 0; mm < 4; mm++)                                     \
        _Pragma("unroll") for (int r = 0; r < 4; r++)                                      \
          p[mm * 4 + r] = __builtin_amdgcn_exp2f(sacc[qs][mm][r] - m_[qs]);                \
      float u0 = (p[0] + p[1]) + (p[2] + p[3]);                                            \
      float u1 = (p[4] + p[5]) + (p[6] + p[7]);                                            \
      float u2 = (p[8] + p[9]) + (p[10] + p[11]);                                          \
      float u3 = (p[12] + p[13]) + (p[14] + p[15]);                                        \
      l_[qs] += (u0 + u1) + (u2 + u3);                                                     \
      _Pragma("unroll") for (int i = 0; i < 8; i++) {                                      \
        int r_;                                                                            \
        asm("v_cvt_pk_bf16_f32 %0, %1, %2" : "=v"(r_) : "v"(p[2 * i]), "v"(p[2 * i + 1])); \
        pb[qs][i >> 2].w[i & 3] = r_;                                                      \
      }                                                                                    \
    }                                                                                      \
  }

  STAGE(0, 0);
  __syncthreads();

  for (int t = 0; t < 32; t++) {
    const int buf = t & 1;
    if (t < 31) STAGE(t + 1, buf ^ 1);

    const char* Kl = lds + buf * 32768 + (kh << 14);
    const char* Vl = Kl + 8192;

    // ---- QK^T (swapped: A=K rows, B=Q): lane holds S[q=lr][k=16m+4g+r] ----
    __builtin_amdgcn_s_setprio(1);
#pragma unroll
    for (int m = 0; m < 4; m++) {
      const char* kp = Kl + (m * 16 + lr) * 128;
      bf16x8 ka0 = *(const bf16x8*)(kp + ((g * 16) ^ swzR));
      bf16x8 ka1 = *(const bf16x8*)(kp + ((64 + g * 16) ^ swzR));
#pragma unroll
      for (int qs = 0; qs < 2; qs++) {
        f32x4 c; c[0] = 0.f; c[1] = 0.f; c[2] = 0.f; c[3] = 0.f;
        c = MFMA16(ka0, qa[qs][0], c);
        c = MFMA16(ka1, qa[qs][1], c);
        sacc[qs][m] = c;
      }
    }
    __builtin_amdgcn_s_setprio(0);

    SOFTMAX_STEP();

    // ---- PV (swapped: A=V^T rows, B=P^T): D[d-local][q=lr] ----
    __builtin_amdgcn_s_setprio(1);
#pragma unroll
    for (int n = 0; n < 4; n++) {
      const char* vp = Vl + (n * 16 + lr) * 128;
      bf16x8 va0 = *(const bf16x8*)(vp + ((g * 16) ^ swzR));
      bf16x8 va1 = *(const bf16x8*)(vp + ((64 + g * 16) ^ swzR));
#pragma unroll
      for (int qs = 0; qs < 2; qs++) {
        oacc[qs][n] = MFMA16(va0, pb[qs][0].v, oacc[qs][n]);
        oacc[qs][n] = MFMA16(va1, pb[qs][1].v, oacc[qs][n]);
      }
    }
    __builtin_amdgcn_s_setprio(0);
    __syncthreads();
  }

  // reduce lane-partial l across the 4 g-lanes of each row
#pragma unroll
  for (int qs = 0; qs < 2; qs++) {
    l_[qs] += __shfl_xor(l_[qs], 16);
    l_[qs] += __shfl_xor(l_[qs], 32);
  }

  // ---- merge kv-halves (partner wave = w^2) ----
  char* mbase = lds + (qh << 14);
  if (kh == 1) {
#pragma unroll
    for (int qs = 0; qs < 2; qs++) {
      const int q = qs * 16 + lr;
      char* rowp = mbase + q * 256;
#pragma unroll
      for (int n = 0; n < 4; n++)
        *(f32x4*)(rowp + ((n * 64 + g * 16) ^ ((lr & 7) << 4))) = oacc[qs][n];
    }
    if (g == 0) {
#pragma unroll
      for (int qs = 0; qs < 2; qs++) {
        float2 ml; ml.x = m_[qs]; ml.y = l_[qs];
        *(float2*)(mbase + 8192 + qs * 128 + lr * 8) = ml;
      }
    }
  }
  __syncthreads();
  if (kh == 0) {
#pragma unroll
    for (int qs = 0; qs < 2; qs++) {
      const float2 ml2 = *(const float2*)(mbase + 8192 + qs * 128 + lr * 8);
      const float mn = fmaxf(m_[qs], ml2.x);
      const float a1 = __builtin_amdgcn_exp2f(m_[qs] - mn);
      const float a2 = __builtin_amdgcn_exp2f(ml2.x - mn);
      const float inv = 1.0f / (l_[qs] * a1 + ml2.y * a2);
      const int q = qs * 16 + lr;
      const char* rowp = mbase + q * 256;
      float* orow = out + ((size_t)batch * S_ + qblk * 64 + qh * 32 + q) * D_;
#pragma unroll
      for (int n = 0; n < 4; n++) {
        f32x4 o2 = *(const f32x4*)(rowp + ((n * 64 + g * 16) ^ ((lr & 7) << 4)));
        f32x4 res = (oacc[qs][n] * a1 + o2 * a2) * inv;
        *(f32x4*)(orow + n * 16 + g * 4) = res;
      }
    }
  }
}

// ---------------------------------------------------------------------------
extern "C" void kernel_launch(void* const* d_in, const int* in_sizes, int n_in,
                              void* d_out, int out_size, void* d_ws, size_t ws_size,
                              hipStream_t stream) {
  const float* x  = (const float*)d_in[0];
  const float* Wq = (const float*)d_in[1];
  const float* bq = (const float*)d_in[2];
  const float* Wk = (const float*)d_in[3];
  const float* bk = (const float*)d_in[4];
  const float* Wv = (const float*)d_in[5];
  const float* bv = (const float*)d_in[6];

  unsigned short* Qb = (unsigned short*)d_ws;            // bf16, pre-scaled log2e/8
  unsigned short* Kb = Qb + (size_t)B_ * S_ * D_;        // bf16 row-major
  unsigned short* Vt = Kb + (size_t)B_ * S_ * D_;        // bf16 [b][d][s], k-permuted

  proj_kernel<<<512, 256, 0, stream>>>(x, Wq, bq, Wk, bk, Wv, bv, Qb, Kb, Vt);
  attn_kernel<<<512, 256, 0, stream>>>(Qb, Kb, Vt, (float*)d_out);
}